// Round 4
// baseline (103.291 us; speedup 1.0000x reference)
//
#include <hip/hip_runtime.h>
#include <stdint.h>

#define M52 0xFFFFFFFFFFFFFULL

__device__ __forceinline__ uint64_t shfl64(uint64_t x, int src) {
    int lo = __shfl((int)(uint32_t)x, src, 64);
    int hi = __shfl((int)(uint32_t)(x >> 32), src, 64);
    return ((uint64_t)(uint32_t)hi << 32) | (uint64_t)(uint32_t)lo;
}

// Exact integer emulation of the gate-level restoring divider.
// pa/pb are position-indexed bit words (bit e = row element e); returns the
// position-indexed result word. Circuit quirks preserved: 13-bit mod-8192
// exponent, dead rounding-carry (mantissa wraps without exponent bump),
// special-case priority NaN > Inf > Zero > Overflow > Underflow.
__device__ __forceinline__ uint64_t circuit_divide(uint64_t pa, uint64_t pb) {
    const uint64_t av = __brevll(pa);
    const uint64_t bv = __brevll(pb);

    const uint32_t s_out = (uint32_t)((av ^ bv) >> 63);
    const uint32_t Ea = (uint32_t)(av >> 52) & 0x7FFu;
    const uint32_t Eb = (uint32_t)(bv >> 52) & 0x7FFu;
    const uint64_t Ma = av & M52;
    const uint64_t Mb = bv & M52;

    const bool ea_all1 = (Ea == 0x7FFu), eb_all1 = (Eb == 0x7FFu);
    const bool ea_zero = (Ea == 0u),     eb_zero = (Eb == 0u);
    const bool ma_zero = (Ma == 0ull),   mb_zero = (Mb == 0ull);
    const bool a_zero = ea_zero && ma_zero, b_zero = eb_zero && mb_zero;
    const bool a_inf  = ea_all1 && ma_zero, b_inf  = eb_all1 && mb_zero;
    const bool a_nan  = ea_all1 && !ma_zero, b_nan = eb_all1 && !mb_zero;

    const bool r_nan  = a_nan || b_nan || (a_zero && b_zero) || (a_inf && b_inf);
    const bool r_inf  = (!a_zero && b_zero) || (a_inf && !b_inf);
    const bool r_zero = (a_zero && !b_zero) || (!a_inf && b_inf);

    const uint32_t exp13 = (Ea - Eb + 1023u) & 0x1FFFu;

    // 57-step restoring division on 55-bit values (R < 2D invariant keeps
    // everything < 2^55 so the circuit's 55-bit truncation is a no-op).
    uint64_t R = (1ULL << 53) | (Ma << 1);
    const uint64_t D = (1ULL << 53) | (Mb << 1);
    uint64_t Q = 0;
    #pragma unroll
    for (int i = 0; i < 56; ++i) {
        const bool ge = (R >= D);
        const uint64_t t = R - D;
        R = ge ? t : R;
        Q = (Q << 1) | (ge ? 1u : 0u);
        R <<= 1;
    }
    {   // final step, no shift
        const bool ge = (R >= D);
        const uint64_t t = R - D;
        R = ge ? t : R;
        Q = (Q << 1) | (ge ? 1u : 0u);
    }

    const uint32_t q0 = (uint32_t)(Q >> 56) & 1u;
    const uint32_t rem_nz = (R != 0ull) ? 1u : 0u;

    const uint64_t mant52 = q0 ? ((Q >> 4) & M52) : ((Q >> 3) & M52);
    const uint32_t rbit   = q0 ? ((uint32_t)(Q >> 3) & 1u) : ((uint32_t)(Q >> 2) & 1u);
    const uint32_t sticky = (q0 ? (((Q & 7ull) != 0ull) ? 1u : 0u)
                                : (((Q & 3ull) != 0ull) ? 1u : 0u)) | rem_nz;
    const uint32_t exp_f  = q0 ? exp13 : ((exp13 - 1u) & 0x1FFFu);

    const uint32_t lsb = (uint32_t)mant52 & 1u;
    const uint32_t rup = rbit & (sticky | lsb);
    const uint64_t mant_final = (mant52 + rup) & M52;

    const uint32_t exp11   = exp_f & 0x7FFu;
    const bool overflow  = (exp_f >> 11) != 0u;
    const bool underflow = (((exp_f >> 12) & 1u) != 0u) || (exp_f == 0u);

    uint64_t res = ((uint64_t)s_out << 63) | ((uint64_t)exp11 << 52) | mant_final;
    const uint64_t zero_v = ((uint64_t)s_out << 63);
    const uint64_t inf_v  = zero_v | (0x7FFULL << 52);
    const uint64_t nan_v  = inf_v | (1ULL << 51);

    if (r_nan)          res = nan_v;
    else if (r_inf)     res = inf_v;
    else if (r_zero)    res = zero_v;
    else if (overflow)  res = inf_v;
    else if (underflow) res = zero_v;

    return __brevll(res);
}

// Two row-chunks per thread, software-pipelined: chunk1's 128 coalesced loads
// are issued BEFORE chunk0's divide/store, so compute+store of chunk0 runs
// with 32 KB/wave of chunk1 reads in flight (read/write streams overlap).
// Lane l always touches element l -> every access is a 256 B wave transaction.
__global__ __launch_bounds__(256, 1) void fp64div_kernel(
    const float* __restrict__ A, const float* __restrict__ B,
    float* __restrict__ out, int half_rows)
{
    const int tid  = blockIdx.x * blockDim.x + threadIdx.x;
    const int lane = threadIdx.x & 63;
    const int wb   = tid & ~63;
    if (wb >= half_rows) return;             // exact grid; never taken

    const size_t off0 = (size_t)wb * 64 + lane;
    const size_t off1 = off0 + (size_t)half_rows * 64;
    const float* Ap0 = A + off0;
    const float* Bp0 = B + off0;
    const float* Ap1 = A + off1;
    const float* Bp1 = B + off1;

    float fa[64], fb[64];

    // ---- chunk0 loads ----
    #pragma unroll
    for (int r = 0; r < 64; ++r) fa[r] = Ap0[(size_t)r * 64];
    #pragma unroll
    for (int r = 0; r < 64; ++r) fb[r] = Bp0[(size_t)r * 64];

    // pack A0 (drains A0 regs), then immediately refill with chunk1 A loads
    uint64_t a0 = 0, b0 = 0;
    #pragma unroll
    for (int r = 0; r < 64; ++r) {
        uint64_t m = __ballot(fa[r] != 0.0f);
        if (lane == r) a0 = m;
    }
    #pragma unroll
    for (int r = 0; r < 64; ++r) fa[r] = Ap1[(size_t)r * 64];   // chunk1 A in flight

    #pragma unroll
    for (int r = 0; r < 64; ++r) {
        uint64_t m = __ballot(fb[r] != 0.0f);
        if (lane == r) b0 = m;
    }
    #pragma unroll
    for (int r = 0; r < 64; ++r) fb[r] = Bp1[(size_t)r * 64];   // chunk1 B in flight

    // ---- chunk0 compute + store (chunk1 loads streaming underneath) ----
    const uint64_t w0 = circuit_divide(a0, b0);
    float* Op0 = out + off0;
    #pragma unroll
    for (int r = 0; r < 64; ++r) {
        const uint64_t w = shfl64(w0, r);
        Op0[(size_t)r * 64] = (float)((uint32_t)(w >> lane) & 1u);
    }

    // ---- chunk1 pack + compute + store ----
    uint64_t a1 = 0, b1 = 0;
    #pragma unroll
    for (int r = 0; r < 64; ++r) {
        uint64_t m = __ballot(fa[r] != 0.0f);
        if (lane == r) a1 = m;
    }
    #pragma unroll
    for (int r = 0; r < 64; ++r) {
        uint64_t m = __ballot(fb[r] != 0.0f);
        if (lane == r) b1 = m;
    }
    const uint64_t w1 = circuit_divide(a1, b1);
    float* Op1 = out + off1;
    #pragma unroll
    for (int r = 0; r < 64; ++r) {
        const uint64_t w = shfl64(w1, r);
        Op1[(size_t)r * 64] = (float)((uint32_t)(w >> lane) & 1u);
    }
}

extern "C" void kernel_launch(void* const* d_in, const int* in_sizes, int n_in,
                              void* d_out, int out_size, void* d_ws, size_t ws_size,
                              hipStream_t stream) {
    const float* A = (const float*)d_in[0];
    const float* B = (const float*)d_in[1];
    float* out = (float*)d_out;
    const int n_rows = in_sizes[0] / 64;
    const int half = n_rows >> 1;
    const int threads = 256;
    const int blocks = (half + threads - 1) / threads;
    fp64div_kernel<<<blocks, threads, 0, stream>>>(A, B, out, half);
}

// Round 5
// 99.038 us; speedup vs baseline: 1.0430x; 1.0430x over previous
//
#include <hip/hip_runtime.h>
#include <stdint.h>

#define M52 0xFFFFFFFFFFFFFULL

__device__ __forceinline__ uint64_t shfl64v(uint64_t x, int src) {
    int lo = __shfl((int)(uint32_t)x, src, 64);
    int hi = __shfl((int)(uint32_t)(x >> 32), src, 64);
    return ((uint64_t)(uint32_t)hi << 32) | (uint64_t)(uint32_t)lo;
}

// Exact integer emulation of the gate-level restoring divider (verified
// absmax=0 in R1-R4). pa/pb position-indexed (bit e = row element e).
// Circuit quirks preserved: 13-bit mod-8192 exponent, dead rounding-carry
// (mantissa wraps without exponent bump), priority NaN>Inf>Zero>Ovf>Unf.
__device__ __forceinline__ uint64_t circuit_divide(uint64_t pa, uint64_t pb) {
    const uint64_t av = __brevll(pa);
    const uint64_t bv = __brevll(pb);

    const uint32_t s_out = (uint32_t)((av ^ bv) >> 63);
    const uint32_t Ea = (uint32_t)(av >> 52) & 0x7FFu;
    const uint32_t Eb = (uint32_t)(bv >> 52) & 0x7FFu;
    const uint64_t Ma = av & M52;
    const uint64_t Mb = bv & M52;

    const bool ea_all1 = (Ea == 0x7FFu), eb_all1 = (Eb == 0x7FFu);
    const bool ea_zero = (Ea == 0u),     eb_zero = (Eb == 0u);
    const bool ma_zero = (Ma == 0ull),   mb_zero = (Mb == 0ull);
    const bool a_zero = ea_zero && ma_zero, b_zero = eb_zero && mb_zero;
    const bool a_inf  = ea_all1 && ma_zero, b_inf  = eb_all1 && mb_zero;
    const bool a_nan  = ea_all1 && !ma_zero, b_nan = eb_all1 && !mb_zero;

    const bool r_nan  = a_nan || b_nan || (a_zero && b_zero) || (a_inf && b_inf);
    const bool r_inf  = (!a_zero && b_zero) || (a_inf && !b_inf);
    const bool r_zero = (a_zero && !b_zero) || (!a_inf && b_inf);

    const uint32_t exp13 = (Ea - Eb + 1023u) & 0x1FFFu;

    uint64_t R = (1ULL << 53) | (Ma << 1);
    const uint64_t D = (1ULL << 53) | (Mb << 1);
    uint64_t Q = 0;
    #pragma unroll
    for (int i = 0; i < 56; ++i) {
        const bool ge = (R >= D);
        const uint64_t t = R - D;
        R = ge ? t : R;
        Q = (Q << 1) | (ge ? 1u : 0u);
        R <<= 1;
    }
    {   // final step, no shift
        const bool ge = (R >= D);
        const uint64_t t = R - D;
        R = ge ? t : R;
        Q = (Q << 1) | (ge ? 1u : 0u);
    }

    const uint32_t q0 = (uint32_t)(Q >> 56) & 1u;
    const uint32_t rem_nz = (R != 0ull) ? 1u : 0u;

    const uint64_t mant52 = q0 ? ((Q >> 4) & M52) : ((Q >> 3) & M52);
    const uint32_t rbit   = q0 ? ((uint32_t)(Q >> 3) & 1u) : ((uint32_t)(Q >> 2) & 1u);
    const uint32_t sticky = (q0 ? (((Q & 7ull) != 0ull) ? 1u : 0u)
                                : (((Q & 3ull) != 0ull) ? 1u : 0u)) | rem_nz;
    const uint32_t exp_f  = q0 ? exp13 : ((exp13 - 1u) & 0x1FFFu);

    const uint32_t lsb = (uint32_t)mant52 & 1u;
    const uint32_t rup = rbit & (sticky | lsb);
    const uint64_t mant_final = (mant52 + rup) & M52;

    const uint32_t exp11   = exp_f & 0x7FFu;
    const bool overflow  = (exp_f >> 11) != 0u;
    const bool underflow = (((exp_f >> 12) & 1u) != 0u) || (exp_f == 0u);

    uint64_t res = ((uint64_t)s_out << 63) | ((uint64_t)exp11 << 52) | mant_final;
    const uint64_t zero_v = ((uint64_t)s_out << 63);
    const uint64_t inf_v  = zero_v | (0x7FFULL << 52);
    const uint64_t nan_v  = inf_v | (1ULL << 51);

    if (r_nan)          res = nan_v;
    else if (r_inf)     res = inf_v;
    else if (r_zero)    res = zero_v;
    else if (overflow)  res = inf_v;
    else if (underflow) res = zero_v;

    return __brevll(res);
}

__device__ __forceinline__ uint32_t compact16(uint32_t d) {
    // 4 nibble-bytes (low nibble valid) -> 16 contiguous bits
    uint32_t t = (d | (d >> 4)) & 0x00FF00FFu;
    return (t | (t >> 8)) & 0x0000FFFFu;
}

// Wave handles 64 consecutive rows. All global accesses are 16 B/lane and
// fully coalesced (1 KB per wave-instruction): load inst i, lane l touches
// rows 4i+(l>>4), elements 4*(l&15)..+3. Transpose to per-lane row words via
// a wave-private nibble buffer in LDS (no barrier needed); inverse transpose
// for stores via ds_bpermute gather. 48 VMEM inst/wave vs 192 in R3.
__global__ __launch_bounds__(256, 2) void fp64div_kernel(
    const uint4* __restrict__ A, const uint4* __restrict__ B,
    uint4* __restrict__ out, int n_rows)
{
    __shared__ uint8_t lds[4][2][1024];
    const int tid  = blockIdx.x * blockDim.x + threadIdx.x;
    const int lane = threadIdx.x & 63;
    const int wid  = threadIdx.x >> 6;
    const int wave = tid >> 6;
    if ((wave << 6) >= n_rows) return;           // exact grid; never taken

    const size_t chunk = (size_t)wave * 1024;    // uint4 units (64 rows)
    const uint4* Ap = A + chunk + lane;
    const uint4* Bp = B + chunk + lane;

    // ---- 32 coalesced 1 KB loads, all in flight ----
    uint4 va[16], vb[16];
    #pragma unroll
    for (int i = 0; i < 16; ++i) va[i] = Ap[i * 64];
    #pragma unroll
    for (int i = 0; i < 16; ++i) vb[i] = Bp[i * 64];

    // ---- nibble-pack into wave-private LDS ----
    // byte [i*64 + l] == row (4i+(l>>4)) nibble (l&15)  ==  byte [16*row + m]
    uint8_t* la = lds[wid][0];
    uint8_t* lb = lds[wid][1];
    #pragma unroll
    for (int i = 0; i < 16; ++i) {
        const uint32_t na = ((va[i].x >> 29) & 1u) | ((va[i].y >> 28) & 2u)
                          | ((va[i].z >> 27) & 4u) | ((va[i].w >> 26) & 8u);
        la[i * 64 + lane] = (uint8_t)na;
        const uint32_t nb = ((vb[i].x >> 29) & 1u) | ((vb[i].y >> 28) & 2u)
                          | ((vb[i].z >> 27) & 4u) | ((vb[i].w >> 26) & 8u);
        lb[i * 64 + lane] = (uint8_t)nb;
    }

    // ---- lane r reads row r's 16 nibbles (one b128), compacts to u64 ----
    const uint4 ra = ((const uint4*)la)[lane];
    const uint4 rb = ((const uint4*)lb)[lane];
    const uint64_t pa = (uint64_t)(compact16(ra.x) | (compact16(ra.y) << 16))
                      | ((uint64_t)(compact16(ra.z) | (compact16(ra.w) << 16)) << 32);
    const uint64_t pb = (uint64_t)(compact16(rb.x) | (compact16(rb.y) << 16))
                      | ((uint64_t)(compact16(rb.z) | (compact16(rb.w) << 16)) << 32);

    const uint64_t w = circuit_divide(pa, pb);

    // ---- store: bpermute-gather word of row 4i+(l>>4), emit 16 B/lane ----
    uint4* Op = out + chunk + lane;
    const int s0   = 4 * (lane & 15);
    const int srcb = lane >> 4;
    #pragma unroll
    for (int i = 0; i < 16; ++i) {
        const uint64_t wr = shfl64v(w, srcb + 4 * i);
        const uint32_t nib = (uint32_t)(wr >> s0) & 0xFu;
        uint4 o;
        o.x = (nib & 1u) ? 0x3F800000u : 0u;
        o.y = (nib & 2u) ? 0x3F800000u : 0u;
        o.z = (nib & 4u) ? 0x3F800000u : 0u;
        o.w = (nib & 8u) ? 0x3F800000u : 0u;
        Op[i * 64] = o;
    }
}

extern "C" void kernel_launch(void* const* d_in, const int* in_sizes, int n_in,
                              void* d_out, int out_size, void* d_ws, size_t ws_size,
                              hipStream_t stream) {
    const uint4* A = (const uint4*)d_in[0];
    const uint4* B = (const uint4*)d_in[1];
    uint4* out = (uint4*)d_out;
    const int n_rows = in_sizes[0] / 64;
    const int threads = 256;
    const int blocks = (n_rows + (threads - 1)) / threads;   // 512 blocks, 2048 waves
    fp64div_kernel<<<blocks, threads, 0, stream>>>(A, B, out, n_rows);
}